// Round 2
// baseline (303.894 us; speedup 1.0000x reference)
//
#include <hip/hip_runtime.h>
#include <hip/hip_bf16.h>
#include <stdint.h>

#define N_USERS   10000
#define N_ITEMS   100000
#define N_FEAT    64
#define EMB_DIM   128
#define SEQ_LEN   50
#define TAU       0.01f

// ---------------------------------------------------------------------------
// Kernel 1: per-sequence weight wt[n]
//   Z[n,s] = dot(R[n,s,:], w);  Wv = max(Z, tau)
//   acc    = sum_s mask ? Wv^alpha : 0 ;  cnt = sum_s mask
//   wt[n]  = ((acc^(1/alpha)) * (cnt^beta))^gamma
// One wave (64 lanes) per sequence. Lane split: f4 = lane&15 covers the 64
// features as float4; sg = lane>>4 covers 4 steps at a time.
// Mask dtype is detected at runtime (int32 / float32 / byte-bool) from the
// first 64 words — branch is grid-uniform and deterministic.
// ---------------------------------------------------------------------------
__global__ __launch_bounds__(256) void wt_kernel(
    const float* __restrict__ R, const void* __restrict__ mask_raw,
    const float* __restrict__ w,
    const float* __restrict__ alpha_p, const float* __restrict__ beta_p,
    const float* __restrict__ gamma_p,
    float* __restrict__ wt_out, int num_seq)
{
    int wave = (blockIdx.x * blockDim.x + threadIdx.x) >> 6;
    int lane = threadIdx.x & 63;
    if (wave >= num_seq) return;   // whole waves retire together (wave id = tid>>6)
    const int n = wave;

    // ---- mask dtype detection (uniform across grid) ----
    const unsigned int* mi = (const unsigned int*)mask_raw;
    unsigned int pv = mi[lane];
    float        pf = __uint_as_float(pv);
    bool allint = __all(pv <= 1u) != 0;                      // int32 0/1 mask
    bool allflt = __all(pf == 0.0f || pf == 1.0f) != 0;      // fp32 0.0/1.0 mask
    const int mode = allint ? 0 : (allflt ? 1 : 2);          // 2 = byte bool

    // ---- load this sequence's mask once into a 64-bit ballot ----
    bool mv = false;
    if (lane < SEQ_LEN) {
        size_t off = (size_t)n * SEQ_LEN + lane;
        if (mode == 0)      mv = ((const int*)mask_raw)[off] != 0;
        else if (mode == 1) mv = ((const float*)mask_raw)[off] != 0.0f;
        else                mv = ((const uint8_t*)mask_raw)[off] != 0;
    }
    unsigned long long mbits = __ballot(mv);

    const float alpha = alpha_p[0];
    const float beta  = beta_p[0];
    const float gamma = gamma_p[0];

    const int f4 = lane & 15;   // which float4 of the 64 features
    const int sg = lane >> 4;   // which of 4 concurrent steps

    const float4 w4 = reinterpret_cast<const float4*>(w)[f4];
    const float4* Rn = reinterpret_cast<const float4*>(R + (size_t)n * SEQ_LEN * N_FEAT);

    float acc = 0.0f;   // identical across the 16 lanes of a step-group
    float cnt = 0.0f;

    #pragma unroll
    for (int s0 = 0; s0 < SEQ_LEN; s0 += 4) {
        int s = s0 + sg;
        bool valid = (s < SEQ_LEN);
        float4 x = make_float4(0.f, 0.f, 0.f, 0.f);
        if (valid) x = Rn[s * (N_FEAT / 4) + f4];
        float d = x.x * w4.x + x.y * w4.y + x.z * w4.z + x.w * w4.w;
        // butterfly over the 16 lanes sharing this step
        d += __shfl_xor(d, 1);
        d += __shfl_xor(d, 2);
        d += __shfl_xor(d, 4);
        d += __shfl_xor(d, 8);
        if (valid && ((mbits >> s) & 1ULL)) {
            float Wv = fmaxf(d, TAU);
            acc += (alpha == 1.0f) ? Wv : powf(Wv, alpha);
            cnt += 1.0f;
        }
    }
    // lanes within a step-group are identical; sum the 4 groups
    acc += __shfl_xor(acc, 16);
    acc += __shfl_xor(acc, 32);
    cnt += __shfl_xor(cnt, 16);
    cnt += __shfl_xor(cnt, 32);

    if (lane == 0) {
        float W_alpha = (alpha == 1.0f) ? acc : powf(acc, 1.0f / alpha);
        float R_beta  = (beta  == 1.0f) ? cnt : powf(cnt, beta);
        float base    = W_alpha * R_beta;
        wt_out[n]     = (gamma == 1.0f) ? base : powf(base, gamma);
    }
}

// ---------------------------------------------------------------------------
// Kernel 2: scatter into per-user accumulators
//   num[u, d] += wt[n] * item_emb[items[n], d];  den[u] += wt[n]
// 128 threads per sequence (one per emb dim).
// ---------------------------------------------------------------------------
__global__ __launch_bounds__(256) void scatter_kernel(
    const int* __restrict__ users, const int* __restrict__ items,
    const float* __restrict__ wt, const float* __restrict__ item_emb,
    float* __restrict__ num, float* __restrict__ den, int num_seq)
{
    int idx = blockIdx.x * blockDim.x + threadIdx.x;
    int n = idx >> 7;          // 128 threads / sequence
    int d = idx & 127;
    if (n >= num_seq) return;

    int u  = users[n];
    int it = items[n];
    float wtn = wt[n];
    float qd  = item_emb[(size_t)it * EMB_DIM + d];
    atomicAdd(&num[(size_t)u * EMB_DIM + d], wtn * qd);
    if (d == 0) atomicAdd(&den[u], wtn);
}

// ---------------------------------------------------------------------------
// Kernel 3: r[n] = dot(num[u], q[n]) / den[u]
// One wave per sequence; lane handles 2 emb dims via float2.
// ---------------------------------------------------------------------------
__global__ __launch_bounds__(256) void final_kernel(
    const int* __restrict__ users, const int* __restrict__ items,
    const float* __restrict__ item_emb,
    const float* __restrict__ num, const float* __restrict__ den,
    float* __restrict__ r, int num_seq)
{
    int wave = (blockIdx.x * blockDim.x + threadIdx.x) >> 6;
    int lane = threadIdx.x & 63;
    if (wave >= num_seq) return;
    const int n = wave;

    int u  = users[n];
    int it = items[n];
    float2 q = reinterpret_cast<const float2*>(item_emb + (size_t)it * EMB_DIM)[lane];
    float2 p = reinterpret_cast<const float2*>(num + (size_t)u * EMB_DIM)[lane];
    float dot = q.x * p.x + q.y * p.y;
    dot += __shfl_xor(dot, 1);
    dot += __shfl_xor(dot, 2);
    dot += __shfl_xor(dot, 4);
    dot += __shfl_xor(dot, 8);
    dot += __shfl_xor(dot, 16);
    dot += __shfl_xor(dot, 32);
    if (lane == 0) r[n] = dot / den[u];
}

extern "C" void kernel_launch(void* const* d_in, const int* in_sizes, int n_in,
                              void* d_out, int out_size, void* d_ws, size_t ws_size,
                              hipStream_t stream)
{
    const int*   users    = (const int*)d_in[0];
    const int*   items    = (const int*)d_in[1];
    const float* R_ui     = (const float*)d_in[2];
    const void*  mask     = d_in[3];              // dtype detected on device
    const float* w        = (const float*)d_in[4];
    const float* item_emb = (const float*)d_in[5];
    const float* alpha    = (const float*)d_in[6];
    const float* beta     = (const float*)d_in[7];
    const float* gamma    = (const float*)d_in[8];

    const int num_seq = in_sizes[0];          // 100000
    float* wt = (float*)d_out;                // reuse d_out as wt scratch;
                                              // final_kernel overwrites it with r
    float* num = (float*)d_ws;                              // [N_USERS][EMB_DIM]
    float* den = (float*)d_ws + (size_t)N_USERS * EMB_DIM;  // [N_USERS]

    // zero the per-user accumulators (graph-capture-safe async memset)
    hipMemsetAsync(d_ws, 0, ((size_t)N_USERS * EMB_DIM + N_USERS) * sizeof(float),
                   stream);

    {   // kernel 1: one wave per sequence, 4 waves per block
        int waves_per_block = 4;
        int blocks = (num_seq + waves_per_block - 1) / waves_per_block;
        wt_kernel<<<blocks, 256, 0, stream>>>(R_ui, mask, w, alpha, beta, gamma,
                                              wt, num_seq);
    }
    {   // kernel 2: 128 threads per sequence
        long long threads = (long long)num_seq * EMB_DIM;
        int blocks = (int)((threads + 255) / 256);
        scatter_kernel<<<blocks, 256, 0, stream>>>(users, items, wt, item_emb,
                                                   num, den, num_seq);
    }
    {   // kernel 3: one wave per sequence
        int waves_per_block = 4;
        int blocks = (num_seq + waves_per_block - 1) / waves_per_block;
        final_kernel<<<blocks, 256, 0, stream>>>(users, items, item_emb,
                                                 num, den, (float*)d_out, num_seq);
    }
}

// Round 4
// 272.851 us; speedup vs baseline: 1.1138x; 1.1138x over previous
//
#include <hip/hip_runtime.h>
#include <hip/hip_bf16.h>
#include <stdint.h>

#define N_USERS   10000
#define N_ITEMS   100000
#define N_FEAT    64
#define EMB_DIM   128
#define SEQ_LEN   50
#define TAU       0.01f

typedef float f32x4 __attribute__((ext_vector_type(4)));   // native clang vector

__device__ inline f32x4 nt_load4(const float* p) {
    return __builtin_nontemporal_load(reinterpret_cast<const f32x4*>(p));
}

// ---------------------------------------------------------------------------
// Kernel 1 (fused): per-sequence weight wt[n] + scatter into user accumulators
//   Z[n,s] = dot(R[n,s,:], w);  Wv = max(Z, tau)
//   acc    = sum_s mask ? Wv^alpha : 0 ;  cnt = sum_s mask
//   wt     = ((acc^(1/alpha)) * (cnt^beta))^gamma
//   num[u,:] += wt * item_emb[items[n],:];  den[u] += wt     (atomics)
// One wave (64 lanes) per sequence. Lane split for the dot: f4 = lane&15
// covers the 64 features as float4; sg = lane>>4 covers 4 steps at a time.
// The wave's loads at iteration k are flat-contiguous: Rn[64k + lane] (1 KB).
// Mask dtype detected at runtime (int32 / fp32 / byte) — grid-uniform branch.
// ---------------------------------------------------------------------------
__global__ __launch_bounds__(256) void wt_scatter_kernel(
    const float* __restrict__ R, const void* __restrict__ mask_raw,
    const float* __restrict__ w,
    const int* __restrict__ users, const int* __restrict__ items,
    const float* __restrict__ item_emb,
    const float* __restrict__ alpha_p, const float* __restrict__ beta_p,
    const float* __restrict__ gamma_p,
    float* __restrict__ num, float* __restrict__ den, int num_seq)
{
    int wave = (blockIdx.x * blockDim.x + threadIdx.x) >> 6;
    int lane = threadIdx.x & 63;
    if (wave >= num_seq) return;   // whole waves retire together
    const int n = wave;

    // hoist the per-sequence scalars early (latency hidden under the stream)
    const int u  = users[n];
    const int it = items[n];

    // ---- mask dtype detection (uniform across grid) ----
    const unsigned int* mi = (const unsigned int*)mask_raw;
    unsigned int pv = mi[lane];
    float        pf = __uint_as_float(pv);
    bool allint = __all(pv <= 1u) != 0;                      // int32 0/1 mask
    bool allflt = __all(pf == 0.0f || pf == 1.0f) != 0;      // fp32 0.0/1.0 mask
    const int mode = allint ? 0 : (allflt ? 1 : 2);          // 2 = byte bool

    // ---- load this sequence's mask once into a 64-bit ballot ----
    bool mv = false;
    if (lane < SEQ_LEN) {
        size_t off = (size_t)n * SEQ_LEN + lane;
        if (mode == 0)      mv = ((const int*)mask_raw)[off] != 0;
        else if (mode == 1) mv = ((const float*)mask_raw)[off] != 0.0f;
        else                mv = ((const uint8_t*)mask_raw)[off] != 0;
    }
    unsigned long long mbits = __ballot(mv);

    const float alpha = alpha_p[0];
    const float beta  = beta_p[0];
    const float gamma = gamma_p[0];

    const int f4 = lane & 15;   // which float4 of the 64 features
    const int sg = lane >> 4;   // which of 4 concurrent steps

    const f32x4 w4 = *reinterpret_cast<const f32x4*>(w + 4 * f4);
    const float* Rn = R + (size_t)n * SEQ_LEN * N_FEAT;

    float acc = 0.0f;   // identical across the 16 lanes of a step-group
    float cnt = 0.0f;

    #pragma unroll
    for (int s0 = 0; s0 < SEQ_LEN; s0 += 4) {
        int s = s0 + sg;
        bool valid = (s < SEQ_LEN);
        f32x4 x = {0.f, 0.f, 0.f, 0.f};
        if (valid) x = nt_load4(Rn + s * N_FEAT + 4 * f4);   // streamed once
        float d = x.x * w4.x + x.y * w4.y + x.z * w4.z + x.w * w4.w;
        // butterfly over the 16 lanes sharing this step
        d += __shfl_xor(d, 1);
        d += __shfl_xor(d, 2);
        d += __shfl_xor(d, 4);
        d += __shfl_xor(d, 8);
        if (valid && ((mbits >> s) & 1ULL)) {
            float Wv = fmaxf(d, TAU);
            acc += (alpha == 1.0f) ? Wv : powf(Wv, alpha);
            cnt += 1.0f;
        }
    }
    // sum the 4 step-groups; afterwards ALL lanes hold the full totals
    acc += __shfl_xor(acc, 16);
    acc += __shfl_xor(acc, 32);
    cnt += __shfl_xor(cnt, 16);
    cnt += __shfl_xor(cnt, 32);

    float W_alpha = (alpha == 1.0f) ? acc : powf(acc, 1.0f / alpha);
    float R_beta  = (beta  == 1.0f) ? cnt : powf(cnt, beta);
    float base    = W_alpha * R_beta;
    float wt      = (gamma == 1.0f) ? base : powf(base, gamma);

    // ---- fused scatter: each lane owns 2 emb dims ----
    const float2 q = reinterpret_cast<const float2*>(item_emb + (size_t)it * EMB_DIM)[lane];
    float* numrow = num + (size_t)u * EMB_DIM;
    atomicAdd(&numrow[2 * lane],     wt * q.x);
    atomicAdd(&numrow[2 * lane + 1], wt * q.y);
    if (lane == 0) atomicAdd(&den[u], wt);
}

// ---------------------------------------------------------------------------
// Kernel 2: r[n] = dot(num[u], q[n]) / den[u]
// One wave per sequence; lane handles 2 emb dims via float2.
// ---------------------------------------------------------------------------
__global__ __launch_bounds__(256) void final_kernel(
    const int* __restrict__ users, const int* __restrict__ items,
    const float* __restrict__ item_emb,
    const float* __restrict__ num, const float* __restrict__ den,
    float* __restrict__ r, int num_seq)
{
    int wave = (blockIdx.x * blockDim.x + threadIdx.x) >> 6;
    int lane = threadIdx.x & 63;
    if (wave >= num_seq) return;
    const int n = wave;

    int u  = users[n];
    int it = items[n];
    float2 q = reinterpret_cast<const float2*>(item_emb + (size_t)it * EMB_DIM)[lane];
    float2 p = reinterpret_cast<const float2*>(num + (size_t)u * EMB_DIM)[lane];
    float dot = q.x * p.x + q.y * p.y;
    dot += __shfl_xor(dot, 1);
    dot += __shfl_xor(dot, 2);
    dot += __shfl_xor(dot, 4);
    dot += __shfl_xor(dot, 8);
    dot += __shfl_xor(dot, 16);
    dot += __shfl_xor(dot, 32);
    if (lane == 0) r[n] = dot / den[u];
}

extern "C" void kernel_launch(void* const* d_in, const int* in_sizes, int n_in,
                              void* d_out, int out_size, void* d_ws, size_t ws_size,
                              hipStream_t stream)
{
    const int*   users    = (const int*)d_in[0];
    const int*   items    = (const int*)d_in[1];
    const float* R_ui     = (const float*)d_in[2];
    const void*  mask     = d_in[3];              // dtype detected on device
    const float* w        = (const float*)d_in[4];
    const float* item_emb = (const float*)d_in[5];
    const float* alpha    = (const float*)d_in[6];
    const float* beta     = (const float*)d_in[7];
    const float* gamma    = (const float*)d_in[8];

    const int num_seq = in_sizes[0];          // 100000
    float* num = (float*)d_ws;                              // [N_USERS][EMB_DIM]
    float* den = (float*)d_ws + (size_t)N_USERS * EMB_DIM;  // [N_USERS]

    // zero the per-user accumulators (graph-capture-safe async memset)
    (void)hipMemsetAsync(d_ws, 0,
                         ((size_t)N_USERS * EMB_DIM + N_USERS) * sizeof(float),
                         stream);

    {   // kernel 1 (fused wt + scatter): one wave per sequence, 4 waves/block
        int waves_per_block = 4;
        int blocks = (num_seq + waves_per_block - 1) / waves_per_block;
        wt_scatter_kernel<<<blocks, 256, 0, stream>>>(R_ui, mask, w, users, items,
                                                      item_emb, alpha, beta, gamma,
                                                      num, den, num_seq);
    }
    {   // kernel 2: one wave per sequence
        int waves_per_block = 4;
        int blocks = (num_seq + waves_per_block - 1) / waves_per_block;
        final_kernel<<<blocks, 256, 0, stream>>>(users, items, item_emb,
                                                 num, den, (float*)d_out, num_seq);
    }
}